// Round 9
// baseline (90.573 us; speedup 1.0000x reference)
//
#include <hip/hip_runtime.h>

#define EMB 512
#define NROWS 10000
#define NPAIRS 65536

typedef __bf16 bf16x8 __attribute__((ext_vector_type(8)));
typedef float  f32x4  __attribute__((ext_vector_type(4)));
typedef unsigned int u32x4 __attribute__((ext_vector_type(4)));

// Split fp32 pair into packed bf16-hi dword and bf16-lo dword (RNE both).
__device__ __forceinline__ void split2(float x0, float x1, unsigned* hw, unsigned* lw) {
    unsigned u0 = __float_as_uint(x0), u1 = __float_as_uint(x1);
    unsigned r0 = u0 + 0x7FFFu + ((u0 >> 16) & 1u);
    unsigned r1 = u1 + 0x7FFFu + ((u1 >> 16) & 1u);
    float h0 = __uint_as_float(r0 & 0xFFFF0000u);
    float h1 = __uint_as_float(r1 & 0xFFFF0000u);
    float l0 = x0 - h0, l1 = x1 - h1;                 // exact
    unsigned v0 = __float_as_uint(l0), v1 = __float_as_uint(l1);
    unsigned s0 = v0 + 0x7FFFu + ((v0 >> 16) & 1u);
    unsigned s1 = v1 + 0x7FFFu + ((v1 >> 16) & 1u);
    *hw = (r0 >> 16) | (r1 & 0xFFFF0000u);
    *lw = (s0 >> 16) | (s1 & 0xFFFF0000u);
}

// ---------------- Kernel 0: pre-fragment W1 and W2 into MFMA lane-order bf16 hi/lo ----------
__global__ __launch_bounds__(256)
void k0_fragment(const float* __restrict__ W1, const float* __restrict__ W2,
                 unsigned short* __restrict__ W1Fhi, unsigned short* __restrict__ W1Flo,
                 unsigned short* __restrict__ W2Fhi, unsigned short* __restrict__ W2Flo)
{
    int e = blockIdx.x * 256 + threadIdx.x;
    float x;
    unsigned short *hp, *lp;
    if (e < 131072) {
        int i  = e & 7;
        int l  = (e >> 3) & 63;
        int nt = (e >> 9) & 7;
        int kt = (e >> 12) & 15;
        int t  = e >> 16;
        int k = kt * 32 + 8 * (l >> 4) + i;
        int n = nt * 16 + (l & 15);
        x = W1[(t * 512 + k) * 128 + n];
        hp = W1Fhi + e; lp = W1Flo + e;
    } else {
        int e2 = e - 131072;
        int i  = e2 & 7;
        int l  = (e2 >> 3) & 63;
        int nt = (e2 >> 9) & 3;
        int kt = e2 >> 11;
        int k = kt * 32 + 8 * (l >> 4) + i;
        int n = nt * 16 + (l & 15);
        x = W2[k * 64 + n];
        hp = W2Fhi + e2; lp = W2Flo + e2;
    }
    unsigned u = __float_as_uint(x);
    unsigned r = u + 0x7FFFu + ((u >> 16) & 1u);
    float hf = __uint_as_float(r & 0xFFFF0000u);
    float lf = x - hf;
    unsigned v = __float_as_uint(lf);
    unsigned s = v + 0x7FFFu + ((v >> 16) & 1u);
    *hp = (unsigned short)(r >> 16);
    *lp = (unsigned short)(s >> 16);
}

// ---------------- Kernel 1: D = drug @ W1[:512,:] + b1, T = tgt @ W1[512:,:] ----------------
// Stage-once structure: whole 32x512 A-tile (64 KB) DMA'd to LDS, ONE sync, then 16
// barrier-free kt-iterations. Swizzle: chunk-space 128 f32x4 per row; LDS[row][c] holds
// global chunk (c&~7)|((c&7)^(row&7)); reads invert with the same XOR. 626 blocks x 4 waves.
#define K1_RT 313

__global__ __launch_bounds__(256)
void k1_mfma(const float* __restrict__ drug, const float* __restrict__ tgt,
             const unsigned* __restrict__ W1Fhi, const unsigned* __restrict__ W1Flo,
             const float* __restrict__ b1,
             float* __restrict__ D, float* __restrict__ T)
{
    __shared__ float Abuf[32 * 512];   // 64 KB

    int bid = blockIdx.x, tid = threadIdx.x;
    bool isT = bid >= K1_RT;
    int rt = isT ? bid - K1_RT : bid;
    const float* emb = isT ? tgt : drug;
    float* out = isT ? T : D;
    int row0 = rt * 32;

    int wave = tid >> 6, lane = tid & 63;
    int g = lane >> 4, lm = lane & 15;
    int mt = wave & 1, nh = wave >> 1;

    // ---- stage all 32 rows x 512 f32: 16 instrs/wave (instr = half a row = 1 KB) ----
    #pragma unroll
    for (int it = 0; it < 16; it++) {
        int pr = wave * 8 + (it >> 1);               // tile row 0..31
        int srow = row0 + pr;
        if (srow > NROWS - 1) srow = NROWS - 1;      // clamp OOB (stores guarded)
        int c = (it & 1) * 64 + lane;                // dest chunk within row
        int sc = (c & ~7) | ((lane & 7) ^ (pr & 7)); // pre-swizzled source chunk
        __builtin_amdgcn_global_load_lds(
            (const __attribute__((address_space(1))) void*)(emb + (size_t)srow * EMB + sc * 4),
            (__attribute__((address_space(3))) void*)((char*)Abuf + wave * 16384 + it * 1024),
            16, 0, 0);
    }
    __syncthreads();   // compiler emits vmcnt(0)+lgkmcnt(0) before s_barrier

    const u32x4* BH = (const u32x4*)W1Fhi + (isT ? 8192 : 0);
    const u32x4* BL = (const u32x4*)W1Flo + (isT ? 8192 : 0);
    const f32x4* A4 = (const f32x4*)Abuf;

    int r = mt * 16 + lm, rk = r & 7;

    f32x4 acc[4];
    #pragma unroll
    for (int j = 0; j < 4; j++) { acc[j][0]=0.f; acc[j][1]=0.f; acc[j][2]=0.f; acc[j][3]=0.f; }

    #pragma unroll 4
    for (int kt = 0; kt < 16; kt++) {
        u32x4 bh[4], bl[4];
        #pragma unroll
        for (int j = 0; j < 4; j++) {
            int nt = nh * 4 + j;
            bh[j] = BH[(kt * 8 + nt) * 64 + lane];
            bl[j] = BL[(kt * 8 + nt) * 64 + lane];
        }
        f32x4 a0 = A4[r * 128 + kt * 8 + ((2 * g)     ^ rk)];
        f32x4 a1 = A4[r * 128 + kt * 8 + ((2 * g + 1) ^ rk)];
        unsigned h0, h1, h2, h3, l0, l1, l2, l3;
        split2(a0[0], a0[1], &h0, &l0);
        split2(a0[2], a0[3], &h1, &l1);
        split2(a1[0], a1[1], &h2, &l2);
        split2(a1[2], a1[3], &h3, &l3);
        u32x4 ah, al;
        ah[0]=h0; ah[1]=h1; ah[2]=h2; ah[3]=h3;
        al[0]=l0; al[1]=l1; al[2]=l2; al[3]=l3;
        bf16x8 Ah = __builtin_bit_cast(bf16x8, ah);
        bf16x8 Al = __builtin_bit_cast(bf16x8, al);
        #pragma unroll
        for (int j = 0; j < 4; j++) {
            bf16x8 Bh = __builtin_bit_cast(bf16x8, bh[j]);
            bf16x8 Bl = __builtin_bit_cast(bf16x8, bl[j]);
            acc[j] = __builtin_amdgcn_mfma_f32_16x16x32_bf16(Ah, Bh, acc[j], 0, 0, 0);
            acc[j] = __builtin_amdgcn_mfma_f32_16x16x32_bf16(Ah, Bl, acc[j], 0, 0, 0);
            acc[j] = __builtin_amdgcn_mfma_f32_16x16x32_bf16(Al, Bh, acc[j], 0, 0, 0);
        }
    }

    // store: C row = mt*16 + 4g + reg, col = nt*16 + lm (verified map)
    #pragma unroll
    for (int j = 0; j < 4; j++) {
        int col = (nh * 4 + j) * 16 + lm;
        float bias = isT ? 0.f : b1[col];
        #pragma unroll
        for (int reg = 0; reg < 4; reg++) {
            int row = row0 + mt * 16 + 4 * g + reg;
            if (row < NROWS) out[row * 128 + col] = acc[j][reg] + bias;
        }
    }
}

// ---------------- Kernel 2: pair loss, stage-once gathers ----------------
// 4096 blocks x 4 waves, 32 pairs/block. Stage ALL 96 rows x 128 f32 (48 KB) in 12
// DMAs/wave, one sync, then 4 barrier-free K-steps. Swizzle: 32-chunk rows,
// LDS[row][c] = global[row][(c&24)|((c&7)^(row&7))]; reads invert identically.
__global__ __launch_bounds__(256)
void k2_pairs(const float* __restrict__ D, const float* __restrict__ T,
              const int* __restrict__ pos, const int* __restrict__ neg,
              const unsigned* __restrict__ W2Fhi, const unsigned* __restrict__ W2Flo,
              const float* __restrict__ b2, const float* __restrict__ W3,
              double* __restrict__ partials)
{
    __shared__ float Sbuf[96 * 128];   // 48 KB
    __shared__ double red[4];

    int tid = threadIdx.x, bid = blockIdx.x;
    int wave = tid >> 6, lane = tid & 63;
    int g = lane >> 4, lm = lane & 15;
    const int* pairs = (bid < 2048) ? pos : neg;
    int p0 = (bid & 2047) * 32;

    // ---- stage: 12 instrs/wave, instr covers rows pr0=wave*24+it*2 (+ lane>>5) ----
    #pragma unroll
    for (int it = 0; it < 12; it++) {
        int pr = wave * 24 + it * 2 + (lane >> 5);
        int idxv;
        const float* src;
        if (pr < 32) { idxv = pairs[(p0 + pr) * 3]; src = D; }
        else { int q = pr - 32; idxv = pairs[(p0 + (q >> 1)) * 3 + 1 + (q & 1)]; src = T; }
        int c = lane & 31;
        int sc = (c & 24) | ((c & 7) ^ (pr & 7));    // pre-swizzled source chunk
        __builtin_amdgcn_global_load_lds(
            (const __attribute__((address_space(1))) void*)(src + (size_t)idxv * 128 + sc * 4),
            (__attribute__((address_space(3))) void*)((char*)Sbuf + wave * 12288 + it * 1024),
            16, 0, 0);
    }
    __syncthreads();   // vmcnt(0) drain + barrier

    const u32x4* BH4 = (const u32x4*)W2Fhi;
    const u32x4* BL4 = (const u32x4*)W2Flo;
    const f32x4* S4 = (const f32x4*)Sbuf;

    int r = wave * 16 + lm;              // this lane's output row (wave = mt)
    int p = r >> 1;                      // d-row (shared by the pair's two sides)
    int pk = p & 7, tk = r & 7;          // read swizzle keys ((32+r)&7 == r&7)

    f32x4 acc[4];
    #pragma unroll
    for (int nt = 0; nt < 4; nt++) { acc[nt][0]=0.f; acc[nt][1]=0.f; acc[nt][2]=0.f; acc[nt][3]=0.f; }

    #pragma unroll
    for (int step = 0; step < 4; step++) {
        u32x4 bh[4], bl[4];
        #pragma unroll
        for (int nt = 0; nt < 4; nt++) {
            bh[nt] = BH4[(step * 4 + nt) * 64 + lane];
            bl[nt] = BL4[(step * 4 + nt) * 64 + lane];
        }
        f32x4 d0 = S4[p * 32 + step * 8 + ((2 * g)     ^ pk)];
        f32x4 d1 = S4[p * 32 + step * 8 + ((2 * g + 1) ^ pk)];
        f32x4 t0 = S4[(32 + r) * 32 + step * 8 + ((2 * g)     ^ tk)];
        f32x4 t1 = S4[(32 + r) * 32 + step * 8 + ((2 * g + 1) ^ tk)];
        float h0 = fmaxf(d0[0] + t0[0], 0.f), h1v = fmaxf(d0[1] + t0[1], 0.f);
        float h2 = fmaxf(d0[2] + t0[2], 0.f), h3 = fmaxf(d0[3] + t0[3], 0.f);
        float h4 = fmaxf(d1[0] + t1[0], 0.f), h5 = fmaxf(d1[1] + t1[1], 0.f);
        float h6 = fmaxf(d1[2] + t1[2], 0.f), h7 = fmaxf(d1[3] + t1[3], 0.f);
        unsigned hq0, hq1, hq2, hq3, lq0, lq1, lq2, lq3;
        split2(h0, h1v, &hq0, &lq0);
        split2(h2, h3,  &hq1, &lq1);
        split2(h4, h5,  &hq2, &lq2);
        split2(h6, h7,  &hq3, &lq3);
        u32x4 ah, al;
        ah[0]=hq0; ah[1]=hq1; ah[2]=hq2; ah[3]=hq3;
        al[0]=lq0; al[1]=lq1; al[2]=lq2; al[3]=lq3;
        bf16x8 Ah = __builtin_bit_cast(bf16x8, ah);
        bf16x8 Al = __builtin_bit_cast(bf16x8, al);
        #pragma unroll
        for (int nt = 0; nt < 4; nt++) {
            bf16x8 Bh = __builtin_bit_cast(bf16x8, bh[nt]);
            bf16x8 Bl = __builtin_bit_cast(bf16x8, bl[nt]);
            acc[nt] = __builtin_amdgcn_mfma_f32_16x16x32_bf16(Ah, Bh, acc[nt], 0, 0, 0);
            acc[nt] = __builtin_amdgcn_mfma_f32_16x16x32_bf16(Ah, Bl, acc[nt], 0, 0, 0);
            acc[nt] = __builtin_amdgcn_mfma_f32_16x16x32_bf16(Al, Bh, acc[nt], 0, 0, 0);
        }
    }

    // ---- epilogue: layer 3 + pair diff (C row = wave*16+4g+reg, col = nt*16+lm) ----
    float b2v[4], w3v[4];
    #pragma unroll
    for (int nt = 0; nt < 4; nt++) { b2v[nt] = b2[nt * 16 + lm]; w3v[nt] = W3[nt * 16 + lm]; }

    float pr[4];
    #pragma unroll
    for (int reg = 0; reg < 4; reg++) {
        float s = 0.f;
        #pragma unroll
        for (int nt = 0; nt < 4; nt++) {
            float h2 = fmaxf(acc[nt][reg] + b2v[nt], 0.f);
            s = fmaf(h2, w3v[nt], s);
        }
        pr[reg] = s;
    }
    #pragma unroll
    for (int m = 1; m <= 8; m <<= 1)
        #pragma unroll
        for (int reg = 0; reg < 4; reg++)
            pr[reg] += __shfl_xor(pr[reg], m, 64);

    float dd0 = pr[0] - pr[1];           // rows 4g+0/1 = one pair
    float dd1 = pr[2] - pr[3];           // rows 4g+2/3 = next pair
    double dsq = (double)dd0 * (double)dd0 + (double)dd1 * (double)dd1;
    dsq += __shfl_xor(dsq, 16, 64);
    dsq += __shfl_xor(dsq, 32, 64);

    if (lane == 0) red[wave] = dsq;
    __syncthreads();
    if (tid == 0) partials[bid] = red[0] + red[1] + red[2] + red[3];
}

// ---------------- Kernel 3: final reduction (4096 partials) ----------------
__global__ __launch_bounds__(256)
void k3_final(const double* __restrict__ partials, float* __restrict__ out)
{
    __shared__ double sred[2][4];
    int t = threadIdx.x;
    double sp = 0.0, sn = 0.0;
    #pragma unroll
    for (int i = 0; i < 8; i++) {
        sp += partials[t + 256 * i];
        sn += partials[2048 + t + 256 * i];
    }
    #pragma unroll
    for (int m = 1; m <= 32; m <<= 1) {
        sp += __shfl_xor(sp, m, 64);
        sn += __shfl_xor(sn, m, 64);
    }
    int wave = t >> 6, lane = t & 63;
    if (lane == 0) { sred[0][wave] = sp; sred[1][wave] = sn; }
    __syncthreads();
    if (t == 0) {
        double SP = sred[0][0] + sred[0][1] + sred[0][2] + sred[0][3];
        double SN = sred[1][0] + sred[1][1] + sred[1][2] + sred[1][3];
        out[0] = (float)((SP - SN) / (double)NPAIRS);
    }
}

extern "C" void kernel_launch(void* const* d_in, const int* in_sizes, int n_in,
                              void* d_out, int out_size, void* d_ws, size_t ws_size,
                              hipStream_t stream) {
    const int*   pos  = (const int*)d_in[0];
    const int*   neg  = (const int*)d_in[1];
    const float* drug = (const float*)d_in[2];
    const float* tgt  = (const float*)d_in[3];
    const float* W1   = (const float*)d_in[4];
    const float* b1   = (const float*)d_in[5];
    const float* W2   = (const float*)d_in[6];
    const float* b2   = (const float*)d_in[7];
    const float* W3   = (const float*)d_in[8];
    // d_in[9] = b3: cancels in a1 - a2, unused

    float* Dp = (float*)d_ws;                       // 10000*128 floats
    float* Tp = Dp + NROWS * 128;                   // 10000*128 floats
    char* base = (char*)(Tp + NROWS * 128);
    unsigned short* W2Fhi = (unsigned short*)base;            // 16 KB
    unsigned short* W2Flo = W2Fhi + 8192;                     // 16 KB
    unsigned short* W1Fhi = W2Flo + 8192;                     // 256 KB
    unsigned short* W1Flo = W1Fhi + 131072;                   // 256 KB
    double* partials = (double*)(W1Flo + 131072);             // 4096 doubles
    float* out = (float*)d_out;

    k0_fragment<<<544, 256, 0, stream>>>(W1, W2, W1Fhi, W1Flo, W2Fhi, W2Flo);
    k1_mfma<<<2 * K1_RT, 256, 0, stream>>>(drug, tgt, (const unsigned*)W1Fhi,
                                           (const unsigned*)W1Flo, b1, Dp, Tp);
    k2_pairs<<<4096, 256, 0, stream>>>(Dp, Tp, pos, neg, (const unsigned*)W2Fhi,
                                       (const unsigned*)W2Flo, b2, W3, partials);
    k3_final<<<1, 256, 0, stream>>>(partials, out);
}

// Round 10
// 68.828 us; speedup vs baseline: 1.3159x; 1.3159x over previous
//
#include <hip/hip_runtime.h>

#define EMB 512
#define NROWS 10000
#define NPAIRS 65536

typedef __bf16 bf16x8 __attribute__((ext_vector_type(8)));
typedef float  f32x4  __attribute__((ext_vector_type(4)));
typedef unsigned int u32x4 __attribute__((ext_vector_type(4)));

// Split fp32 pair into packed bf16-hi dword and bf16-lo dword (RNE both).
__device__ __forceinline__ void split2(float x0, float x1, unsigned* hw, unsigned* lw) {
    unsigned u0 = __float_as_uint(x0), u1 = __float_as_uint(x1);
    unsigned r0 = u0 + 0x7FFFu + ((u0 >> 16) & 1u);
    unsigned r1 = u1 + 0x7FFFu + ((u1 >> 16) & 1u);
    float h0 = __uint_as_float(r0 & 0xFFFF0000u);
    float h1 = __uint_as_float(r1 & 0xFFFF0000u);
    float l0 = x0 - h0, l1 = x1 - h1;                 // exact
    unsigned v0 = __float_as_uint(l0), v1 = __float_as_uint(l1);
    unsigned s0 = v0 + 0x7FFFu + ((v0 >> 16) & 1u);
    unsigned s1 = v1 + 0x7FFFu + ((v1 >> 16) & 1u);
    *hw = (r0 >> 16) | (r1 & 0xFFFF0000u);
    *lw = (s0 >> 16) | (s1 & 0xFFFF0000u);
}

// ---------------- Kernel 0: pre-fragment W1 and W2 into MFMA lane-order bf16 hi/lo ----------
__global__ __launch_bounds__(256)
void k0_fragment(const float* __restrict__ W1, const float* __restrict__ W2,
                 unsigned short* __restrict__ W1Fhi, unsigned short* __restrict__ W1Flo,
                 unsigned short* __restrict__ W2Fhi, unsigned short* __restrict__ W2Flo)
{
    int e = blockIdx.x * 256 + threadIdx.x;
    float x;
    unsigned short *hp, *lp;
    if (e < 131072) {
        int i  = e & 7;
        int l  = (e >> 3) & 63;
        int nt = (e >> 9) & 7;
        int kt = (e >> 12) & 15;
        int t  = e >> 16;
        int k = kt * 32 + 8 * (l >> 4) + i;
        int n = nt * 16 + (l & 15);
        x = W1[(t * 512 + k) * 128 + n];
        hp = W1Fhi + e; lp = W1Flo + e;
    } else {
        int e2 = e - 131072;
        int i  = e2 & 7;
        int l  = (e2 >> 3) & 63;
        int nt = (e2 >> 9) & 3;
        int kt = e2 >> 11;
        int k = kt * 32 + 8 * (l >> 4) + i;
        int n = nt * 16 + (l & 15);
        x = W2[k * 64 + n];
        hp = W2Fhi + e2; lp = W2Flo + e2;
    }
    unsigned u = __float_as_uint(x);
    unsigned r = u + 0x7FFFu + ((u >> 16) & 1u);
    float hf = __uint_as_float(r & 0xFFFF0000u);
    float lf = x - hf;
    unsigned v = __float_as_uint(lf);
    unsigned s = v + 0x7FFFu + ((v >> 16) & 1u);
    *hp = (unsigned short)(r >> 16);
    *lp = (unsigned short)(s >> 16);
}

// ---------------- Kernel 1: D = drug @ W1[:512,:] + b1, T = tgt @ W1[512:,:] ----------------
// No-LDS split-bf16 MFMA with a PINNED depth-2 register pipeline: per kt, issue kt+1's
// 6 loads, sched_barrier(0), then split+6 MFMA on kt's regs, sched_barrier(0). The
// auto-waitcnt before kt+1's first use becomes a counted vmcnt(6) — loads fly under MFMA.
// Grid: 2 tables x 625 tiles of 16 rows (10000 = 625*16, no bounds checks). 4 waves/block,
// wave = 16 rows x 32 cols (ntb = 2*wave).
#define K1_TILES 625

__global__ __launch_bounds__(256)
void k1_mfma(const float* __restrict__ drug, const float* __restrict__ tgt,
             const unsigned* __restrict__ W1Fhi, const unsigned* __restrict__ W1Flo,
             const float* __restrict__ b1,
             float* __restrict__ D, float* __restrict__ T)
{
    int bid = blockIdx.x, tid = threadIdx.x;
    bool isT = bid >= K1_TILES;
    int rt = isT ? bid - K1_TILES : bid;
    const float* emb = isT ? tgt : drug;
    float* out = isT ? T : D;
    int row0 = rt * 16;

    int wave = tid >> 6, lane = tid & 63;
    int g = lane >> 4, lm = lane & 15;
    int ntb = wave * 2;                 // this wave's 2 N-tiles

    const u32x4* BH = (const u32x4*)W1Fhi + (isT ? 8192 : 0);
    const u32x4* BL = (const u32x4*)W1Flo + (isT ? 8192 : 0);

    const float* abase = emb + (size_t)(row0 + lm) * EMB + 8 * g;

    f32x4 acc[2];
    #pragma unroll
    for (int j = 0; j < 2; j++) { acc[j][0]=0.f; acc[j][1]=0.f; acc[j][2]=0.f; acc[j][3]=0.f; }

    // prologue: kt=0 loads
    float4 a0c = *(const float4*)(abase);
    float4 a1c = *(const float4*)(abase + 4);
    u32x4 bh0c = BH[ntb * 64 + lane];
    u32x4 bh1c = BH[(ntb + 1) * 64 + lane];
    u32x4 bl0c = BL[ntb * 64 + lane];
    u32x4 bl1c = BL[(ntb + 1) * 64 + lane];
    __builtin_amdgcn_sched_barrier(0);

    #pragma unroll
    for (int kt = 0; kt < 16; kt++) {
        float4 a0n, a1n;
        u32x4 bh0n, bh1n, bl0n, bl1n;
        if (kt < 15) {   // compile-time under full unroll
            a0n = *(const float4*)(abase + (kt + 1) * 32);
            a1n = *(const float4*)(abase + (kt + 1) * 32 + 4);
            bh0n = BH[((kt + 1) * 8 + ntb) * 64 + lane];
            bh1n = BH[((kt + 1) * 8 + ntb + 1) * 64 + lane];
            bl0n = BL[((kt + 1) * 8 + ntb) * 64 + lane];
            bl1n = BL[((kt + 1) * 8 + ntb + 1) * 64 + lane];
        }
        __builtin_amdgcn_sched_barrier(0);   // loads pinned above; compute below
        unsigned h0, h1, h2, h3, l0, l1, l2, l3;
        split2(a0c.x, a0c.y, &h0, &l0);
        split2(a0c.z, a0c.w, &h1, &l1);
        split2(a1c.x, a1c.y, &h2, &l2);
        split2(a1c.z, a1c.w, &h3, &l3);
        u32x4 ah, al;
        ah[0]=h0; ah[1]=h1; ah[2]=h2; ah[3]=h3;
        al[0]=l0; al[1]=l1; al[2]=l2; al[3]=l3;
        bf16x8 Ah = __builtin_bit_cast(bf16x8, ah);
        bf16x8 Al = __builtin_bit_cast(bf16x8, al);
        bf16x8 Bh0 = __builtin_bit_cast(bf16x8, bh0c);
        bf16x8 Bh1 = __builtin_bit_cast(bf16x8, bh1c);
        bf16x8 Bl0 = __builtin_bit_cast(bf16x8, bl0c);
        bf16x8 Bl1 = __builtin_bit_cast(bf16x8, bl1c);
        acc[0] = __builtin_amdgcn_mfma_f32_16x16x32_bf16(Ah, Bh0, acc[0], 0, 0, 0);
        acc[1] = __builtin_amdgcn_mfma_f32_16x16x32_bf16(Ah, Bh1, acc[1], 0, 0, 0);
        acc[0] = __builtin_amdgcn_mfma_f32_16x16x32_bf16(Ah, Bl0, acc[0], 0, 0, 0);
        acc[1] = __builtin_amdgcn_mfma_f32_16x16x32_bf16(Ah, Bl1, acc[1], 0, 0, 0);
        acc[0] = __builtin_amdgcn_mfma_f32_16x16x32_bf16(Al, Bh0, acc[0], 0, 0, 0);
        acc[1] = __builtin_amdgcn_mfma_f32_16x16x32_bf16(Al, Bh1, acc[1], 0, 0, 0);
        __builtin_amdgcn_sched_barrier(0);   // keep compute region closed
        a0c = a0n; a1c = a1n;
        bh0c = bh0n; bh1c = bh1n; bl0c = bl0n; bl1c = bl1n;
    }

    // store: C row = row0 + 4g + reg, col = (ntb+j)*16 + lm (verified map)
    #pragma unroll
    for (int j = 0; j < 2; j++) {
        int col = (ntb + j) * 16 + lm;
        float bias = isT ? 0.f : b1[col];
        #pragma unroll
        for (int reg = 0; reg < 4; reg++) {
            int row = row0 + 4 * g + reg;
            out[row * 128 + col] = acc[j][reg] + bias;
        }
    }
}

// ---------------- Kernel 2: pair loss via split-bf16 MFMA, DMA-staged gathers ----------------
// R6 structure (measured best ~19us): 1024 blocks x 4 independent waves, 32 pairs/wave,
// per-kt 12x global_load_lds burst + vmcnt(0), wave-private 12 KB, src-pre-swizzled chunks.
__global__ __launch_bounds__(256)
void k2_pairs(const float* __restrict__ D, const float* __restrict__ T,
              const int* __restrict__ pos, const int* __restrict__ neg,
              const unsigned* __restrict__ W2Fhi, const unsigned* __restrict__ W2Flo,
              const float* __restrict__ b2, const float* __restrict__ W3,
              double* __restrict__ partials)
{
    __shared__ u32x4 Ash[4][768];   // 48 KB: per-wave 12 KB = 96 rows x 8 float4 (one 32-k slice)

    int tid = threadIdx.x;
    int wave = tid >> 6, lane = tid & 63;
    int g = lane >> 4, lm = lane & 15;
    int rr = lane >> 3, cc = lane & 7;
    int gw = blockIdx.x * 4 + wave;              // 0..4095
    const int* pairs = (gw < 2048) ? pos : neg;  // blocks 0..511 pos, 512..1023 neg
    int p0 = (gw & 2047) * 32;

    const float* bp[12];
    #pragma unroll
    for (int it = 0; it < 12; it++) {
        int pr = it * 8 + rr;
        int idxv;
        const float* src;
        if (pr < 32) { idxv = pairs[(p0 + pr) * 3]; src = D; }
        else { int q = pr - 32; idxv = pairs[(p0 + (q >> 1)) * 3 + 1 + (q & 1)]; src = T; }
        bp[it] = src + (size_t)idxv * 128 + ((cc ^ (pr & 7)) << 2);
    }

    u32x4* A4w = &Ash[wave][0];
    const u32x4* BH4 = (const u32x4*)W2Fhi;
    const u32x4* BL4 = (const u32x4*)W2Flo;

    f32x4 acc[4][4];
    #pragma unroll
    for (int mt = 0; mt < 4; mt++)
        #pragma unroll
        for (int nt = 0; nt < 4; nt++) { acc[mt][nt][0]=0.f; acc[mt][nt][1]=0.f; acc[mt][nt][2]=0.f; acc[mt][nt][3]=0.f; }

    #pragma unroll 1
    for (int kt = 0; kt < 4; kt++) {
        u32x4 bh[4], bl[4];
        #pragma unroll
        for (int nt = 0; nt < 4; nt++) {
            bh[nt] = BH4[(kt * 4 + nt) * 64 + lane];
            bl[nt] = BL4[(kt * 4 + nt) * 64 + lane];
        }
        #pragma unroll
        for (int it = 0; it < 12; it++) {
            __builtin_amdgcn_global_load_lds(
                (const __attribute__((address_space(1))) void*)(bp[it] + kt * 32),
                (__attribute__((address_space(3))) void*)((char*)A4w + it * 1024),
                16, 0, 0);
        }
        asm volatile("s_waitcnt vmcnt(0)" ::: "memory");
        #pragma unroll
        for (int mt = 0; mt < 4; mt++) {
            int r = mt * 16 + lm;
            int p = r >> 1;
            int ds = p & 7, ts = r & 7;
            const f32x4* drow = (const f32x4*)(A4w + p * 8);
            const f32x4* trow = (const f32x4*)(A4w + (32 + r) * 8);
            f32x4 d0 = drow[(2 * g) ^ ds];
            f32x4 d1 = drow[(2 * g + 1) ^ ds];
            f32x4 t0 = trow[(2 * g) ^ ts];
            f32x4 t1 = trow[(2 * g + 1) ^ ts];
            float h0 = fmaxf(d0[0] + t0[0], 0.f), h1v = fmaxf(d0[1] + t0[1], 0.f);
            float h2 = fmaxf(d0[2] + t0[2], 0.f), h3 = fmaxf(d0[3] + t0[3], 0.f);
            float h4 = fmaxf(d1[0] + t1[0], 0.f), h5 = fmaxf(d1[1] + t1[1], 0.f);
            float h6 = fmaxf(d1[2] + t1[2], 0.f), h7 = fmaxf(d1[3] + t1[3], 0.f);
            unsigned hq0, hq1, hq2, hq3, lq0, lq1, lq2, lq3;
            split2(h0, h1v, &hq0, &lq0);
            split2(h2, h3,  &hq1, &lq1);
            split2(h4, h5,  &hq2, &lq2);
            split2(h6, h7,  &hq3, &lq3);
            u32x4 ah, al;
            ah[0]=hq0; ah[1]=hq1; ah[2]=hq2; ah[3]=hq3;
            al[0]=lq0; al[1]=lq1; al[2]=lq2; al[3]=lq3;
            bf16x8 Ah = __builtin_bit_cast(bf16x8, ah);
            bf16x8 Al = __builtin_bit_cast(bf16x8, al);
            #pragma unroll
            for (int nt = 0; nt < 4; nt++) {
                bf16x8 Bh = __builtin_bit_cast(bf16x8, bh[nt]);
                bf16x8 Bl = __builtin_bit_cast(bf16x8, bl[nt]);
                acc[mt][nt] = __builtin_amdgcn_mfma_f32_16x16x32_bf16(Ah, Bh, acc[mt][nt], 0, 0, 0);
                acc[mt][nt] = __builtin_amdgcn_mfma_f32_16x16x32_bf16(Ah, Bl, acc[mt][nt], 0, 0, 0);
                acc[mt][nt] = __builtin_amdgcn_mfma_f32_16x16x32_bf16(Al, Bh, acc[mt][nt], 0, 0, 0);
            }
        }
        asm volatile("s_waitcnt lgkmcnt(0)" ::: "memory");
    }

    float b2v[4], w3v[4];
    #pragma unroll
    for (int nt = 0; nt < 4; nt++) { b2v[nt] = b2[nt * 16 + lm]; w3v[nt] = W3[nt * 16 + lm]; }

    float pr[4][4];
    #pragma unroll
    for (int mt = 0; mt < 4; mt++)
        #pragma unroll
        for (int reg = 0; reg < 4; reg++) {
            float s = 0.f;
            #pragma unroll
            for (int nt = 0; nt < 4; nt++) {
                float h2 = fmaxf(acc[mt][nt][reg] + b2v[nt], 0.f);
                s = fmaf(h2, w3v[nt], s);
            }
            pr[mt][reg] = s;
        }
    #pragma unroll
    for (int m = 1; m <= 8; m <<= 1)
        #pragma unroll
        for (int mt = 0; mt < 4; mt++)
            #pragma unroll
            for (int reg = 0; reg < 4; reg++)
                pr[mt][reg] += __shfl_xor(pr[mt][reg], m, 64);

    double dsq = 0.0;
    #pragma unroll
    for (int mt = 0; mt < 4; mt++) {
        float d0 = pr[mt][0] - pr[mt][1];
        float d1 = pr[mt][2] - pr[mt][3];
        dsq += (double)d0 * (double)d0 + (double)d1 * (double)d1;
    }
    dsq += __shfl_xor(dsq, 16, 64);
    dsq += __shfl_xor(dsq, 32, 64);

    __syncthreads();
    if (lane == 0) ((double*)&Ash[wave][0])[0] = dsq;
    __syncthreads();
    if (tid == 0) {
        double sum = 0.0;
        #pragma unroll
        for (int w = 0; w < 4; w++) sum += ((double*)&Ash[w][0])[0];
        partials[blockIdx.x] = sum;   // 0..511 pos, 512..1023 neg
    }
}

// ---------------- Kernel 3: final reduction (1024 partials) ----------------
__global__ void k3_final(const double* __restrict__ partials, float* __restrict__ out)
{
    int lane = threadIdx.x;  // 64 threads
    double sp = 0.0, sn = 0.0;
    #pragma unroll
    for (int i = 0; i < 8; i++) {
        sp += partials[lane + 64 * i];
        sn += partials[512 + lane + 64 * i];
    }
    #pragma unroll
    for (int m = 1; m <= 32; m <<= 1) {
        sp += __shfl_xor(sp, m, 64);
        sn += __shfl_xor(sn, m, 64);
    }
    if (lane == 0) out[0] = (float)((sp - sn) / (double)NPAIRS);
}

extern "C" void kernel_launch(void* const* d_in, const int* in_sizes, int n_in,
                              void* d_out, int out_size, void* d_ws, size_t ws_size,
                              hipStream_t stream) {
    const int*   pos  = (const int*)d_in[0];
    const int*   neg  = (const int*)d_in[1];
    const float* drug = (const float*)d_in[2];
    const float* tgt  = (const float*)d_in[3];
    const float* W1   = (const float*)d_in[4];
    const float* b1   = (const float*)d_in[5];
    const float* W2   = (const float*)d_in[6];
    const float* b2   = (const float*)d_in[7];
    const float* W3   = (const float*)d_in[8];
    // d_in[9] = b3: cancels in a1 - a2, unused

    float* Dp = (float*)d_ws;                       // 10000*128 floats
    float* Tp = Dp + NROWS * 128;                   // 10000*128 floats
    char* base = (char*)(Tp + NROWS * 128);
    unsigned short* W2Fhi = (unsigned short*)base;            // 16 KB
    unsigned short* W2Flo = W2Fhi + 8192;                     // 16 KB
    unsigned short* W1Fhi = W2Flo + 8192;                     // 256 KB
    unsigned short* W1Flo = W1Fhi + 131072;                   // 256 KB
    double* partials = (double*)(W1Flo + 131072);             // 1024 doubles
    float* out = (float*)d_out;

    k0_fragment<<<544, 256, 0, stream>>>(W1, W2, W1Fhi, W1Flo, W2Fhi, W2Flo);
    k1_mfma<<<2 * K1_TILES, 256, 0, stream>>>(drug, tgt, (const unsigned*)W1Fhi,
                                              (const unsigned*)W1Flo, b1, Dp, Tp);
    k2_pairs<<<1024, 256, 0, stream>>>(Dp, Tp, pos, neg, (const unsigned*)W2Fhi,
                                       (const unsigned*)W2Flo, b2, W3, partials);
    k3_final<<<1, 64, 0, stream>>>(partials, out);
}

// Round 11
// 65.548 us; speedup vs baseline: 1.3818x; 1.0500x over previous
//
#include <hip/hip_runtime.h>

#define EMB 512
#define NROWS 10000
#define NPAIRS 65536

typedef __bf16 bf16x8 __attribute__((ext_vector_type(8)));
typedef float  f32x4  __attribute__((ext_vector_type(4)));
typedef unsigned int u32x4 __attribute__((ext_vector_type(4)));

// Split fp32 pair into packed bf16-hi dword and bf16-lo dword (RNE both).
__device__ __forceinline__ void split2(float x0, float x1, unsigned* hw, unsigned* lw) {
    unsigned u0 = __float_as_uint(x0), u1 = __float_as_uint(x1);
    unsigned r0 = u0 + 0x7FFFu + ((u0 >> 16) & 1u);
    unsigned r1 = u1 + 0x7FFFu + ((u1 >> 16) & 1u);
    float h0 = __uint_as_float(r0 & 0xFFFF0000u);
    float h1 = __uint_as_float(r1 & 0xFFFF0000u);
    float l0 = x0 - h0, l1 = x1 - h1;                 // exact
    unsigned v0 = __float_as_uint(l0), v1 = __float_as_uint(l1);
    unsigned s0 = v0 + 0x7FFFu + ((v0 >> 16) & 1u);
    unsigned s1 = v1 + 0x7FFFu + ((v1 >> 16) & 1u);
    *hw = (r0 >> 16) | (r1 & 0xFFFF0000u);
    *lw = (s0 >> 16) | (s1 & 0xFFFF0000u);
}

// ---------------- Kernel 0: pre-fragment W1 and W2 into MFMA lane-order bf16 hi/lo ----------
__global__ __launch_bounds__(256)
void k0_fragment(const float* __restrict__ W1, const float* __restrict__ W2,
                 unsigned short* __restrict__ W1Fhi, unsigned short* __restrict__ W1Flo,
                 unsigned short* __restrict__ W2Fhi, unsigned short* __restrict__ W2Flo)
{
    int e = blockIdx.x * 256 + threadIdx.x;
    float x;
    unsigned short *hp, *lp;
    if (e < 131072) {
        int i  = e & 7;
        int l  = (e >> 3) & 63;
        int nt = (e >> 9) & 7;
        int kt = (e >> 12) & 15;
        int t  = e >> 16;
        int k = kt * 32 + 8 * (l >> 4) + i;
        int n = nt * 16 + (l & 15);
        x = W1[(t * 512 + k) * 128 + n];
        hp = W1Fhi + e; lp = W1Flo + e;
    } else {
        int e2 = e - 131072;
        int i  = e2 & 7;
        int l  = (e2 >> 3) & 63;
        int nt = (e2 >> 9) & 3;
        int kt = e2 >> 11;
        int k = kt * 32 + 8 * (l >> 4) + i;
        int n = nt * 16 + (l & 15);
        x = W2[k * 64 + n];
        hp = W2Fhi + e2; lp = W2Flo + e2;
    }
    unsigned u = __float_as_uint(x);
    unsigned r = u + 0x7FFFu + ((u >> 16) & 1u);
    float hf = __uint_as_float(r & 0xFFFF0000u);
    float lf = x - hf;
    unsigned v = __float_as_uint(lf);
    unsigned s = v + 0x7FFFu + ((v >> 16) & 1u);
    *hp = (unsigned short)(r >> 16);
    *lp = (unsigned short)(s >> 16);
}

// ---------------- Kernel 1: D = drug @ W1[:512,:] + b1, T = tgt @ W1[512:,:] ----------------
// Stage-once (R8 k1, ~12us): whole 32x512 A-tile (64 KB) DMA'd to LDS in 16 instrs/wave,
// ONE sync, then 16 barrier-free kt-iterations. All 16 staging DMAs in flight at once
// -> one HBM latency exposure per block (vs 16 for any per-kt scheme).
// Swizzle: LDS[row][c] = global[row][(c&~7)|((c&7)^(row&7))]; reads invert identically.
#define K1_RT 313

__global__ __launch_bounds__(256)
void k1_mfma(const float* __restrict__ drug, const float* __restrict__ tgt,
             const unsigned* __restrict__ W1Fhi, const unsigned* __restrict__ W1Flo,
             const float* __restrict__ b1,
             float* __restrict__ D, float* __restrict__ T)
{
    __shared__ float Abuf[32 * 512];   // 64 KB

    int bid = blockIdx.x, tid = threadIdx.x;
    bool isT = bid >= K1_RT;
    int rt = isT ? bid - K1_RT : bid;
    const float* emb = isT ? tgt : drug;
    float* out = isT ? T : D;
    int row0 = rt * 32;

    int wave = tid >> 6, lane = tid & 63;
    int g = lane >> 4, lm = lane & 15;
    int mt = wave & 1, nh = wave >> 1;

    // ---- stage all 32 rows x 512 f32: 16 instrs/wave (instr = half a row = 1 KB) ----
    #pragma unroll
    for (int it = 0; it < 16; it++) {
        int pr = wave * 8 + (it >> 1);               // tile row 0..31
        int srow = row0 + pr;
        if (srow > NROWS - 1) srow = NROWS - 1;      // clamp OOB (stores guarded)
        int c = (it & 1) * 64 + lane;                // dest chunk within row
        int sc = (c & ~7) | ((lane & 7) ^ (pr & 7)); // pre-swizzled source chunk
        __builtin_amdgcn_global_load_lds(
            (const __attribute__((address_space(1))) void*)(emb + (size_t)srow * EMB + sc * 4),
            (__attribute__((address_space(3))) void*)((char*)Abuf + wave * 16384 + it * 1024),
            16, 0, 0);
    }
    __syncthreads();   // compiler emits vmcnt(0) drain before s_barrier

    const u32x4* BH = (const u32x4*)W1Fhi + (isT ? 8192 : 0);
    const u32x4* BL = (const u32x4*)W1Flo + (isT ? 8192 : 0);
    const f32x4* A4 = (const f32x4*)Abuf;

    int r = mt * 16 + lm, rk = r & 7;

    f32x4 acc[4];
    #pragma unroll
    for (int j = 0; j < 4; j++) { acc[j][0]=0.f; acc[j][1]=0.f; acc[j][2]=0.f; acc[j][3]=0.f; }

    #pragma unroll 4
    for (int kt = 0; kt < 16; kt++) {
        u32x4 bh[4], bl[4];
        #pragma unroll
        for (int j = 0; j < 4; j++) {
            int nt = nh * 4 + j;
            bh[j] = BH[(kt * 8 + nt) * 64 + lane];
            bl[j] = BL[(kt * 8 + nt) * 64 + lane];
        }
        f32x4 a0 = A4[r * 128 + kt * 8 + ((2 * g)     ^ rk)];
        f32x4 a1 = A4[r * 128 + kt * 8 + ((2 * g + 1) ^ rk)];
        unsigned h0, h1, h2, h3, l0, l1, l2, l3;
        split2(a0[0], a0[1], &h0, &l0);
        split2(a0[2], a0[3], &h1, &l1);
        split2(a1[0], a1[1], &h2, &l2);
        split2(a1[2], a1[3], &h3, &l3);
        u32x4 ah, al;
        ah[0]=h0; ah[1]=h1; ah[2]=h2; ah[3]=h3;
        al[0]=l0; al[1]=l1; al[2]=l2; al[3]=l3;
        bf16x8 Ah = __builtin_bit_cast(bf16x8, ah);
        bf16x8 Al = __builtin_bit_cast(bf16x8, al);
        #pragma unroll
        for (int j = 0; j < 4; j++) {
            bf16x8 Bh = __builtin_bit_cast(bf16x8, bh[j]);
            bf16x8 Bl = __builtin_bit_cast(bf16x8, bl[j]);
            acc[j] = __builtin_amdgcn_mfma_f32_16x16x32_bf16(Ah, Bh, acc[j], 0, 0, 0);
            acc[j] = __builtin_amdgcn_mfma_f32_16x16x32_bf16(Ah, Bl, acc[j], 0, 0, 0);
            acc[j] = __builtin_amdgcn_mfma_f32_16x16x32_bf16(Al, Bh, acc[j], 0, 0, 0);
        }
    }

    // store: C row = mt*16 + 4g + reg, col = nt*16 + lm (verified map)
    #pragma unroll
    for (int j = 0; j < 4; j++) {
        int col = (nh * 4 + j) * 16 + lm;
        float bias = isT ? 0.f : b1[col];
        #pragma unroll
        for (int reg = 0; reg < 4; reg++) {
            int row = row0 + mt * 16 + 4 * g + reg;
            if (row < NROWS) out[row * 128 + col] = acc[j][reg] + bias;
        }
    }
}

// ---------------- Kernel 2: pair loss via split-bf16 MFMA, DMA-staged gathers ----------------
// R6 structure (measured best ~19us): 1024 blocks x 4 independent waves, 32 pairs/wave,
// per-kt 12x global_load_lds burst + vmcnt(0), wave-private 12 KB, src-pre-swizzled chunks.
__global__ __launch_bounds__(256)
void k2_pairs(const float* __restrict__ D, const float* __restrict__ T,
              const int* __restrict__ pos, const int* __restrict__ neg,
              const unsigned* __restrict__ W2Fhi, const unsigned* __restrict__ W2Flo,
              const float* __restrict__ b2, const float* __restrict__ W3,
              double* __restrict__ partials)
{
    __shared__ u32x4 Ash[4][768];   // 48 KB: per-wave 12 KB = 96 rows x 8 float4 (one 32-k slice)

    int tid = threadIdx.x;
    int wave = tid >> 6, lane = tid & 63;
    int g = lane >> 4, lm = lane & 15;
    int rr = lane >> 3, cc = lane & 7;
    int gw = blockIdx.x * 4 + wave;              // 0..4095
    const int* pairs = (gw < 2048) ? pos : neg;  // blocks 0..511 pos, 512..1023 neg
    int p0 = (gw & 2047) * 32;

    const float* bp[12];
    #pragma unroll
    for (int it = 0; it < 12; it++) {
        int pr = it * 8 + rr;
        int idxv;
        const float* src;
        if (pr < 32) { idxv = pairs[(p0 + pr) * 3]; src = D; }
        else { int q = pr - 32; idxv = pairs[(p0 + (q >> 1)) * 3 + 1 + (q & 1)]; src = T; }
        bp[it] = src + (size_t)idxv * 128 + ((cc ^ (pr & 7)) << 2);
    }

    u32x4* A4w = &Ash[wave][0];
    const u32x4* BH4 = (const u32x4*)W2Fhi;
    const u32x4* BL4 = (const u32x4*)W2Flo;

    f32x4 acc[4][4];
    #pragma unroll
    for (int mt = 0; mt < 4; mt++)
        #pragma unroll
        for (int nt = 0; nt < 4; nt++) { acc[mt][nt][0]=0.f; acc[mt][nt][1]=0.f; acc[mt][nt][2]=0.f; acc[mt][nt][3]=0.f; }

    #pragma unroll 1
    for (int kt = 0; kt < 4; kt++) {
        u32x4 bh[4], bl[4];
        #pragma unroll
        for (int nt = 0; nt < 4; nt++) {
            bh[nt] = BH4[(kt * 4 + nt) * 64 + lane];
            bl[nt] = BL4[(kt * 4 + nt) * 64 + lane];
        }
        #pragma unroll
        for (int it = 0; it < 12; it++) {
            __builtin_amdgcn_global_load_lds(
                (const __attribute__((address_space(1))) void*)(bp[it] + kt * 32),
                (__attribute__((address_space(3))) void*)((char*)A4w + it * 1024),
                16, 0, 0);
        }
        asm volatile("s_waitcnt vmcnt(0)" ::: "memory");
        #pragma unroll
        for (int mt = 0; mt < 4; mt++) {
            int r = mt * 16 + lm;
            int p = r >> 1;
            int ds = p & 7, ts = r & 7;
            const f32x4* drow = (const f32x4*)(A4w + p * 8);
            const f32x4* trow = (const f32x4*)(A4w + (32 + r) * 8);
            f32x4 d0 = drow[(2 * g) ^ ds];
            f32x4 d1 = drow[(2 * g + 1) ^ ds];
            f32x4 t0 = trow[(2 * g) ^ ts];
            f32x4 t1 = trow[(2 * g + 1) ^ ts];
            float h0 = fmaxf(d0[0] + t0[0], 0.f), h1v = fmaxf(d0[1] + t0[1], 0.f);
            float h2 = fmaxf(d0[2] + t0[2], 0.f), h3 = fmaxf(d0[3] + t0[3], 0.f);
            float h4 = fmaxf(d1[0] + t1[0], 0.f), h5 = fmaxf(d1[1] + t1[1], 0.f);
            float h6 = fmaxf(d1[2] + t1[2], 0.f), h7 = fmaxf(d1[3] + t1[3], 0.f);
            unsigned hq0, hq1, hq2, hq3, lq0, lq1, lq2, lq3;
            split2(h0, h1v, &hq0, &lq0);
            split2(h2, h3,  &hq1, &lq1);
            split2(h4, h5,  &hq2, &lq2);
            split2(h6, h7,  &hq3, &lq3);
            u32x4 ah, al;
            ah[0]=hq0; ah[1]=hq1; ah[2]=hq2; ah[3]=hq3;
            al[0]=lq0; al[1]=lq1; al[2]=lq2; al[3]=lq3;
            bf16x8 Ah = __builtin_bit_cast(bf16x8, ah);
            bf16x8 Al = __builtin_bit_cast(bf16x8, al);
            #pragma unroll
            for (int nt = 0; nt < 4; nt++) {
                bf16x8 Bh = __builtin_bit_cast(bf16x8, bh[nt]);
                bf16x8 Bl = __builtin_bit_cast(bf16x8, bl[nt]);
                acc[mt][nt] = __builtin_amdgcn_mfma_f32_16x16x32_bf16(Ah, Bh, acc[mt][nt], 0, 0, 0);
                acc[mt][nt] = __builtin_amdgcn_mfma_f32_16x16x32_bf16(Ah, Bl, acc[mt][nt], 0, 0, 0);
                acc[mt][nt] = __builtin_amdgcn_mfma_f32_16x16x32_bf16(Al, Bh, acc[mt][nt], 0, 0, 0);
            }
        }
        asm volatile("s_waitcnt lgkmcnt(0)" ::: "memory");
    }

    float b2v[4], w3v[4];
    #pragma unroll
    for (int nt = 0; nt < 4; nt++) { b2v[nt] = b2[nt * 16 + lm]; w3v[nt] = W3[nt * 16 + lm]; }

    float pr[4][4];
    #pragma unroll
    for (int mt = 0; mt < 4; mt++)
        #pragma unroll
        for (int reg = 0; reg < 4; reg++) {
            float s = 0.f;
            #pragma unroll
            for (int nt = 0; nt < 4; nt++) {
                float h2 = fmaxf(acc[mt][nt][reg] + b2v[nt], 0.f);
                s = fmaf(h2, w3v[nt], s);
            }
            pr[mt][reg] = s;
        }
    #pragma unroll
    for (int m = 1; m <= 8; m <<= 1)
        #pragma unroll
        for (int mt = 0; mt < 4; mt++)
            #pragma unroll
            for (int reg = 0; reg < 4; reg++)
                pr[mt][reg] += __shfl_xor(pr[mt][reg], m, 64);

    double dsq = 0.0;
    #pragma unroll
    for (int mt = 0; mt < 4; mt++) {
        float d0 = pr[mt][0] - pr[mt][1];
        float d1 = pr[mt][2] - pr[mt][3];
        dsq += (double)d0 * (double)d0 + (double)d1 * (double)d1;
    }
    dsq += __shfl_xor(dsq, 16, 64);
    dsq += __shfl_xor(dsq, 32, 64);

    __syncthreads();
    if (lane == 0) ((double*)&Ash[wave][0])[0] = dsq;
    __syncthreads();
    if (tid == 0) {
        double sum = 0.0;
        #pragma unroll
        for (int w = 0; w < 4; w++) sum += ((double*)&Ash[w][0])[0];
        partials[blockIdx.x] = sum;   // 0..511 pos, 512..1023 neg
    }
}

// ---------------- Kernel 3: final reduction (1024 partials) ----------------
__global__ void k3_final(const double* __restrict__ partials, float* __restrict__ out)
{
    int lane = threadIdx.x;  // 64 threads
    double sp = 0.0, sn = 0.0;
    #pragma unroll
    for (int i = 0; i < 8; i++) {
        sp += partials[lane + 64 * i];
        sn += partials[512 + lane + 64 * i];
    }
    #pragma unroll
    for (int m = 1; m <= 32; m <<= 1) {
        sp += __shfl_xor(sp, m, 64);
        sn += __shfl_xor(sn, m, 64);
    }
    if (lane == 0) out[0] = (float)((sp - sn) / (double)NPAIRS);
}

extern "C" void kernel_launch(void* const* d_in, const int* in_sizes, int n_in,
                              void* d_out, int out_size, void* d_ws, size_t ws_size,
                              hipStream_t stream) {
    const int*   pos  = (const int*)d_in[0];
    const int*   neg  = (const int*)d_in[1];
    const float* drug = (const float*)d_in[2];
    const float* tgt  = (const float*)d_in[3];
    const float* W1   = (const float*)d_in[4];
    const float* b1   = (const float*)d_in[5];
    const float* W2   = (const float*)d_in[6];
    const float* b2   = (const float*)d_in[7];
    const float* W3   = (const float*)d_in[8];
    // d_in[9] = b3: cancels in a1 - a2, unused

    float* Dp = (float*)d_ws;                       // 10000*128 floats
    float* Tp = Dp + NROWS * 128;                   // 10000*128 floats
    char* base = (char*)(Tp + NROWS * 128);
    unsigned short* W2Fhi = (unsigned short*)base;            // 16 KB
    unsigned short* W2Flo = W2Fhi + 8192;                     // 16 KB
    unsigned short* W1Fhi = W2Flo + 8192;                     // 256 KB
    unsigned short* W1Flo = W1Fhi + 131072;                   // 256 KB
    double* partials = (double*)(W1Flo + 131072);             // 1024 doubles
    float* out = (float*)d_out;

    k0_fragment<<<544, 256, 0, stream>>>(W1, W2, W1Fhi, W1Flo, W2Fhi, W2Flo);
    k1_mfma<<<2 * K1_RT, 256, 0, stream>>>(drug, tgt, (const unsigned*)W1Fhi,
                                           (const unsigned*)W1Flo, b1, Dp, Tp);
    k2_pairs<<<1024, 256, 0, stream>>>(Dp, Tp, pos, neg, (const unsigned*)W2Fhi,
                                       (const unsigned*)W2Flo, b2, W3, partials);
    k3_final<<<1, 64, 0, stream>>>(partials, out);
}